// Round 10
// baseline (332.146 us; speedup 1.0000x reference)
//
#include <hip/hip_runtime.h>
#include <hip/hip_bf16.h>

// QuantizedLinear: out[M,O] = x[M,K] @ W[O,K]^T + bias, W 4-bit group-quant (G=64)
// M=8192, O=4096, K=4096.
// Round 10: round-8 schedule (8-phase single-barrier, same staging + vmcnt algebra)
// with fragment reads CLUSTERED at each 4-phase group's head (ph1: Atop+Bright+Bleft,
// ph2: Abot into separate regs a2). Quads at ph2/3/4 use regs >=1 phase old -> no
// lgkm stall; only ph1's quad waits. Targets the read->MFMA serialization residue
// (r9 showed barriers are not the cost; LDS only 27% busy; MFMA floor 58%).

typedef short short8 __attribute__((ext_vector_type(8)));
typedef float float4v __attribute__((ext_vector_type(4)));
typedef int int4v __attribute__((ext_vector_type(4)));

#define M_TOTAL 8192
#define N_OUT 4096
#define K_IN 4096
#define BM 256
#define BN 256
#define BK 64
#define NT (K_IN / BK) // 64 K-tiles

// RTNE float->bf16
__device__ __forceinline__ short f2bf(float f) {
  unsigned int u = __builtin_bit_cast(unsigned int, f);
  unsigned int r = (u + 0x7fffu + ((u >> 16) & 1u)) >> 16;
  return (short)(unsigned short)r;
}

__device__ __forceinline__ void gload_lds16(const void* g, void* l) {
  __builtin_amdgcn_global_load_lds(
      (const __attribute__((address_space(1))) void*)g,
      (__attribute__((address_space(3))) void*)l, 16, 0, 0);
}

// ---------------- prepass 1: x f32 -> bf16 ----------------
__global__ __launch_bounds__(256)
void cvt_x_kernel(const float* __restrict__ x, short* __restrict__ xb, int n8) {
  int i = blockIdx.x * blockDim.x + threadIdx.x;
  int stride = gridDim.x * blockDim.x;
  for (; i < n8; i += stride) {
    const float* p = x + (size_t)i * 8;
    float4v f0 = *reinterpret_cast<const float4v*>(p);
    float4v f1 = *reinterpret_cast<const float4v*>(p + 4);
    short8 v;
#pragma unroll
    for (int e = 0; e < 4; ++e) { v[e] = f2bf(f0[e]); v[4 + e] = f2bf(f1[e]); }
    *reinterpret_cast<short8*>(xb + (size_t)i * 8) = v;
  }
}

// ---------------- prepass 2: W 4-bit -> bf16 [O][K] ----------------
__global__ __launch_bounds__(256)
void deq_w_kernel(const int* __restrict__ wp, const float* __restrict__ wsc,
                  const float* __restrict__ wzr, short* __restrict__ wb) {
  int t = blockIdx.x * blockDim.x + threadIdx.x; // 0..524287
  int g = t >> 1, h = t & 1;
  float s = wsc[g], z = wzr[g];
  const int* p = wp + (size_t)g * 32 + h * 16;
  int4v b[4];
#pragma unroll
  for (int u = 0; u < 4; ++u) b[u] = *reinterpret_cast<const int4v*>(p + u * 4);
  short* o = wb + (size_t)t * 32;
#pragma unroll
  for (int u = 0; u < 4; ++u) {
    short8 v;
#pragma unroll
    for (int e = 0; e < 4; ++e) {
      int bb = b[u][e];
      v[2 * e]     = f2bf((float)(bb & 15) * s + z);
      v[2 * e + 1] = f2bf((float)((bb >> 4) & 15) * s + z);
    }
    *reinterpret_cast<short8*>(o + u * 8) = v;
  }
}

// ---------------- main GEMM: 256x256 tile, 8-phase, clustered reads ----------------
#define MFMA_BF16 __builtin_amdgcn_mfma_f32_16x16x32_bf16
#define BAR() __builtin_amdgcn_s_barrier()
#define PRIO1() __builtin_amdgcn_s_setprio(1)
#define PRIO0() __builtin_amdgcn_s_setprio(0)
#define VMCNT6() asm volatile("s_waitcnt vmcnt(6)" ::: "memory")
#define VMCNT0() asm volatile("s_waitcnt vmcnt(0)" ::: "memory")

__global__ __launch_bounds__(512, 2)
void qgemm8_kernel(const short* __restrict__ A, const short* __restrict__ B,
                   const float* __restrict__ bias, float* __restrict__ out) {
  __shared__ __align__(16) char L[131072];

  const int tid  = threadIdx.x;
  const int lane = tid & 63;
  const int w    = tid >> 6;  // 0..7
  const int wm   = w >> 2;    // 0..1  (M half)
  const int wn   = w & 3;     // 0..3  (N quarter)

  // XCD-chunked swizzle over 512 blocks (2 dispatch rounds of 256).
  const int id  = blockIdx.x;
  const int xcd = id & 7;
  const int s   = id >> 3;   // 0..63
  const int by  = (s >> 5) * 16 + 2 * xcd + ((s & 31) >> 4);
  const int bx  = s & 15;
  const int m0  = by * BM;
  const int o0  = bx * BN;

  // ---- staging precompute (per thread) ----
  const int kslot = (lane & 7) ^ ((lane >> 3) & 7);     // pre-swizzled global k-slot
  const int R0 = w * 16 + (lane >> 3);                  // piece row q=0 (0..127)
  const int R1 = R0 + 8;                                // piece row q=1
  const short* pA0 = A + (size_t)(m0 + (R0 >> 6) * 128 + (R0 & 63)) * K_IN + kslot * 8;
  const short* pA1 = A + (size_t)(m0 + (R1 >> 6) * 128 + (R1 & 63)) * K_IN + kslot * 8;
  const short* pB0 = B + (size_t)(o0 + (R0 >> 5) * 64 + (R0 & 31)) * K_IN + kslot * 8;
  const short* pB1 = B + (size_t)(o0 + (R1 >> 5) * 64 + (R1 & 31)) * K_IN + kslot * 8;
  const int ldsp0 = w * 2048 + lane * 16;               // linear LDS piece dest (bytes)
  const int ldsp1 = ldsp0 + 1024;

#define STAGE_A(buf, mg, t) do { \
    gload_lds16(pA0 + (size_t)(mg) * 64 * K_IN + (t) * 64, &L[(buf) * 65536 + (mg) * 16384 + ldsp0]); \
    gload_lds16(pA1 + (size_t)(mg) * 64 * K_IN + (t) * 64, &L[(buf) * 65536 + (mg) * 16384 + ldsp1]); \
  } while (0)
#define STAGE_B(buf, ng, t) do { \
    gload_lds16(pB0 + (size_t)(ng) * 32 * K_IN + (t) * 64, &L[(buf) * 65536 + 32768 + (ng) * 16384 + ldsp0]); \
    gload_lds16(pB1 + (size_t)(ng) * 32 * K_IN + (t) * 64, &L[(buf) * 65536 + 32768 + (ng) * 16384 + ldsp1]); \
  } while (0)

  // ---- fragment-read precompute ----
  const int l15   = lane & 15;
  const int abase = wm * 8192 + l15 * 128;          // within A region [wh][64r][128B]
  const int bbase = 32768 + wn * 4096 + l15 * 128;  // within B region [128r][128B]
  const int sl0 = (((lane >> 4) + 0) ^ (lane & 7)) * 16; // swizzled 16B slot, ks=0
  const int sl1 = (((lane >> 4) + 4) ^ (lane & 7)) * 16; // ks=1

  short8 a[8], a2[8], bl[4], br[4];

#define RD_A(dst, buf, mg) do { \
    _Pragma("unroll") for (int mf = 0; mf < 4; ++mf) { \
      dst[mf * 2 + 0] = *reinterpret_cast<const short8*>(&L[(buf) * 65536 + (mg) * 16384 + abase + mf * 2048 + sl0]); \
      dst[mf * 2 + 1] = *reinterpret_cast<const short8*>(&L[(buf) * 65536 + (mg) * 16384 + abase + mf * 2048 + sl1]); \
    } } while (0)
#define RD_B(dst, buf, ng) do { \
    _Pragma("unroll") for (int nf = 0; nf < 2; ++nf) { \
      dst[nf * 2 + 0] = *reinterpret_cast<const short8*>(&L[(buf) * 65536 + (ng) * 16384 + bbase + nf * 2048 + sl0]); \
      dst[nf * 2 + 1] = *reinterpret_cast<const short8*>(&L[(buf) * 65536 + (ng) * 16384 + bbase + nf * 2048 + sl1]); \
    } } while (0)

  float4v acc[8][4];
#pragma unroll
  for (int i = 0; i < 8; ++i)
#pragma unroll
    for (int j = 0; j < 4; ++j) acc[i][j] = (float4v){0.f, 0.f, 0.f, 0.f};

  // quad on M-group mg using A regs aa_, N-group ng using B regs bb_
#define DO_QUAD(aa_, mg, ng, bb_) do { \
    _Pragma("unroll") for (int ks = 0; ks < 2; ++ks) \
    _Pragma("unroll") for (int mf = 0; mf < 4; ++mf) \
    _Pragma("unroll") for (int nf = 0; nf < 2; ++nf) \
      acc[(mg) * 4 + mf][(ng) * 2 + nf] = \
        MFMA_BF16(aa_[mf * 2 + ks], bb_[nf * 2 + ks], acc[(mg) * 4 + mf][(ng) * 2 + nf], 0, 0, 0); \
  } while (0)

  // ---- prologue: kt0 (4 chunks, buf0) + kt1 tops (3 chunks, buf1) ----
  STAGE_A(0, 0, 0); STAGE_B(0, 1, 0); STAGE_B(0, 0, 0); STAGE_A(0, 1, 0);
  STAGE_A(1, 0, 1); STAGE_B(1, 1, 1); STAGE_B(1, 0, 1);
  VMCNT6();  // oldest 4 chunks (= all of kt0) landed
  BAR();

  // ---- main loop: i=0..30 computes kt=2i (buf0), kt+1 (buf1) ----
  // Reads clustered at group head; staging/vmcnt identical to round 8.
  for (int i = 0; i < NT / 2 - 1; ++i) {
    const int t2 = 2 * i + 2, t3 = 2 * i + 3;
    // ph1: read ALL buf0 frags except Abot | stage Abot(kt+1)->buf1 | Q1
    RD_A(a, 0, 0); RD_B(br, 0, 1); RD_B(bl, 0, 0);
    STAGE_A(1, 1, t3 - 2);
    PRIO1(); DO_QUAD(a, 0, 1, br); PRIO0(); BAR();
    // ph2: read Abot (a2) | stage kt+2.Atop->buf0 | Q2 (no lgkm wait)
    RD_A(a2, 0, 1);
    STAGE_A(0, 0, t2);
    PRIO1(); DO_QUAD(a, 0, 0, bl); PRIO0(); BAR();
    // ph3: stage kt+2.Bright->buf0 | Q3 (no wait)
    STAGE_B(0, 1, t2);
    PRIO1(); DO_QUAD(a2, 1, 0, bl); PRIO0(); BAR();
    // ph4: stage kt+2.Bleft->buf0 | Q4 (no wait) | vmcnt(6)
    STAGE_B(0, 0, t2);
    PRIO1(); DO_QUAD(a2, 1, 1, br); PRIO0();
    VMCNT6();  // kt+1 fully landed before ph5 reads buf1
    BAR();
    // ph5: read ALL buf1 frags except Abot | stage kt+2.Abot->buf0 | Q1
    RD_A(a, 1, 0); RD_B(br, 1, 1); RD_B(bl, 1, 0);
    STAGE_A(0, 1, t2);
    PRIO1(); DO_QUAD(a, 0, 1, br); PRIO0(); BAR();
    // ph6: read Abot (a2) | stage kt+3.Atop->buf1 | Q2
    RD_A(a2, 1, 1);
    STAGE_A(1, 0, t3);
    PRIO1(); DO_QUAD(a, 0, 0, bl); PRIO0(); BAR();
    // ph7: stage kt+3.Bright->buf1 | Q3
    STAGE_B(1, 1, t3);
    PRIO1(); DO_QUAD(a2, 1, 0, bl); PRIO0(); BAR();
    // ph8: stage kt+3.Bleft->buf1 | Q4 | vmcnt(6)
    STAGE_B(1, 0, t3);
    PRIO1(); DO_QUAD(a2, 1, 1, br); PRIO0();
    VMCNT6();  // kt+2 fully landed before next ph1 reads buf0
    BAR();
  }

  // ---- epilogue: kt=62 (buf0), kt=63 (buf1) ----
  RD_A(a, 0, 0); RD_B(br, 0, 1); RD_B(bl, 0, 0);
  STAGE_A(1, 1, 63);  // kt63.Abot
  PRIO1(); DO_QUAD(a, 0, 1, br); PRIO0(); BAR();
  RD_A(a2, 0, 1);
  PRIO1(); DO_QUAD(a, 0, 0, bl); PRIO0(); BAR();
  PRIO1(); DO_QUAD(a2, 1, 0, bl); PRIO0();
  VMCNT0();  // kt63 fully landed before buf1 reads
  BAR();
  PRIO1(); DO_QUAD(a2, 1, 1, br); PRIO0(); BAR();
  RD_A(a, 1, 0); RD_B(br, 1, 1); RD_B(bl, 1, 0);
  PRIO1(); DO_QUAD(a, 0, 1, br); PRIO0(); BAR();
  RD_A(a2, 1, 1);
  PRIO1(); DO_QUAD(a, 0, 0, bl); PRIO0(); BAR();
  PRIO1(); DO_QUAD(a2, 1, 0, bl); PRIO0(); BAR();
  PRIO1(); DO_QUAD(a2, 1, 1, br); PRIO0();

  // ---- C write: col = o0 + wn*64 + nf*16 + (lane&15); row = m0 + wm*128 + mf*16 + (lane>>4)*4 + r
#pragma unroll
  for (int nf = 0; nf < 4; ++nf) {
    const int col = o0 + wn * 64 + nf * 16 + l15;
    const float bb = bias[col];
#pragma unroll
    for (int mf = 0; mf < 8; ++mf) {
      const int rowb = m0 + wm * 128 + mf * 16 + (lane >> 4) * 4;
#pragma unroll
      for (int r = 0; r < 4; ++r)
        out[(size_t)(rowb + r) * N_OUT + col] = acc[mf][nf][r] + bb;
    }
  }
}

extern "C" void kernel_launch(void* const* d_in, const int* in_sizes, int n_in,
                              void* d_out, int out_size, void* d_ws, size_t ws_size,
                              hipStream_t stream) {
  const float* x    = (const float*)d_in[0];
  const int* wp     = (const int*)d_in[1];
  const float* wsc  = (const float*)d_in[2];
  const float* wzr  = (const float*)d_in[3];
  const float* bias = (const float*)d_in[4];
  float* out = (float*)d_out;

  const size_t xb_bytes = (size_t)M_TOTAL * K_IN * 2;
  short* xb = (short*)d_ws;
  short* wb = (short*)((char*)d_ws + xb_bytes);

  cvt_x_kernel<<<2048, 256, 0, stream>>>(x, xb, (int)((size_t)M_TOTAL * K_IN / 8));
  deq_w_kernel<<<2048, 256, 0, stream>>>(wp, wsc, wzr, wb);
  qgemm8_kernel<<<dim3(512), dim3(512), 0, stream>>>(xb, wb, bias, out);
}

// Round 12
// 268.591 us; speedup vs baseline: 1.2366x; 1.2366x over previous
//
#include <hip/hip_runtime.h>
#include <hip/hip_bf16.h>

// QuantizedLinear: out[M,O] = x[M,K] @ W[O,K]^T + bias, W 4-bit group-quant (G=64)
// M=8192, O=4096, K=4096.
// Round 12: exact round-8 GEMM (verified 227.6us, MfmaUtil 54.5, 0 conflicts) +
// prepasses merged into ONE kernel launch (saves an inter-kernel gap).
// Closed ideas (measured): 32x32 MFMA (4-way bank conflict), persistent/bridge
// (spill), extra-reg prefetch (spill), tail reads (cross-wave LDS race, R11 FAIL),
// 4-phase merge (neutral), nt stores (unrelated regression). Register budget is
// saturated: 128 AGPR acc + ~128 VGPR = 2 waves/SIMD exactly, no headroom.

typedef short short8 __attribute__((ext_vector_type(8)));
typedef float float4v __attribute__((ext_vector_type(4)));
typedef int int4v __attribute__((ext_vector_type(4)));

#define M_TOTAL 8192
#define N_OUT 4096
#define K_IN 4096
#define BM 256
#define BN 256
#define BK 64
#define NT (K_IN / BK) // 64 K-tiles

// RTNE float->bf16
__device__ __forceinline__ short f2bf(float f) {
  unsigned int u = __builtin_bit_cast(unsigned int, f);
  unsigned int r = (u + 0x7fffu + ((u >> 16) & 1u)) >> 16;
  return (short)(unsigned short)r;
}

__device__ __forceinline__ void gload_lds16(const void* g, void* l) {
  __builtin_amdgcn_global_load_lds(
      (const __attribute__((address_space(1))) void*)g,
      (__attribute__((address_space(3))) void*)l, 16, 0, 0);
}

// ---------------- merged prepass: W dequant (blocks 0..2047) | x cvt (blocks 2048..4095) ----------------
__global__ __launch_bounds__(256)
void prep_kernel(const float* __restrict__ x, short* __restrict__ xb,
                 const int* __restrict__ wp, const float* __restrict__ wsc,
                 const float* __restrict__ wzr, short* __restrict__ wb) {
  const int tid = threadIdx.x;
  if (blockIdx.x < 2048) {
    // W 4-bit -> bf16 [O][K]; thread t handles half a group (32 bf16 out)
    int t = blockIdx.x * 256 + tid; // 0..524287
    int g = t >> 1, h = t & 1;
    float s = wsc[g], z = wzr[g];
    const int* p = wp + (size_t)g * 32 + h * 16;
    int4v b[4];
#pragma unroll
    for (int u = 0; u < 4; ++u) b[u] = *reinterpret_cast<const int4v*>(p + u * 4);
    short* o = wb + (size_t)t * 32;
#pragma unroll
    for (int u = 0; u < 4; ++u) {
      short8 v;
#pragma unroll
      for (int e = 0; e < 4; ++e) {
        int bb = b[u][e];
        v[2 * e]     = f2bf((float)(bb & 15) * s + z);
        v[2 * e + 1] = f2bf((float)((bb >> 4) & 15) * s + z);
      }
      *reinterpret_cast<short8*>(o + u * 8) = v;
    }
  } else {
    // x f32 -> bf16, grid-stride over groups of 8 floats
    const int n8 = (int)((size_t)M_TOTAL * K_IN / 8); // 4194304
    int i = (blockIdx.x - 2048) * 256 + tid;
    const int stride = 2048 * 256;
    for (; i < n8; i += stride) {
      const float* p = x + (size_t)i * 8;
      float4v f0 = *reinterpret_cast<const float4v*>(p);
      float4v f1 = *reinterpret_cast<const float4v*>(p + 4);
      short8 v;
#pragma unroll
      for (int e = 0; e < 4; ++e) { v[e] = f2bf(f0[e]); v[4 + e] = f2bf(f1[e]); }
      *reinterpret_cast<short8*>(xb + (size_t)i * 8) = v;
    }
  }
}

// ---------------- main GEMM: 256x256 tile, 8-phase single-barrier, 8 waves ----------------
#define MFMA_BF16 __builtin_amdgcn_mfma_f32_16x16x32_bf16
#define BAR() __builtin_amdgcn_s_barrier()
#define PRIO1() __builtin_amdgcn_s_setprio(1)
#define PRIO0() __builtin_amdgcn_s_setprio(0)
#define VMCNT6() asm volatile("s_waitcnt vmcnt(6)" ::: "memory")
#define VMCNT0() asm volatile("s_waitcnt vmcnt(0)" ::: "memory")

__global__ __launch_bounds__(512, 2)
void qgemm8_kernel(const short* __restrict__ A, const short* __restrict__ B,
                   const float* __restrict__ bias, float* __restrict__ out) {
  __shared__ __align__(16) char L[131072];

  const int tid  = threadIdx.x;
  const int lane = tid & 63;
  const int w    = tid >> 6;  // 0..7
  const int wm   = w >> 2;    // 0..1  (M half)
  const int wn   = w & 3;     // 0..3  (N quarter)

  // XCD-chunked swizzle over 512 blocks (2 dispatch rounds of 256).
  const int id  = blockIdx.x;
  const int xcd = id & 7;
  const int s   = id >> 3;   // 0..63
  const int by  = (s >> 5) * 16 + 2 * xcd + ((s & 31) >> 4);
  const int bx  = s & 15;
  const int m0  = by * BM;
  const int o0  = bx * BN;

  // ---- staging precompute (per thread) ----
  const int kslot = (lane & 7) ^ ((lane >> 3) & 7);     // pre-swizzled global k-slot
  const int R0 = w * 16 + (lane >> 3);                  // piece row q=0 (0..127)
  const int R1 = R0 + 8;                                // piece row q=1
  const short* pA0 = A + (size_t)(m0 + (R0 >> 6) * 128 + (R0 & 63)) * K_IN + kslot * 8;
  const short* pA1 = A + (size_t)(m0 + (R1 >> 6) * 128 + (R1 & 63)) * K_IN + kslot * 8;
  const short* pB0 = B + (size_t)(o0 + (R0 >> 5) * 64 + (R0 & 31)) * K_IN + kslot * 8;
  const short* pB1 = B + (size_t)(o0 + (R1 >> 5) * 64 + (R1 & 31)) * K_IN + kslot * 8;
  const int ldsp0 = w * 2048 + lane * 16;               // linear LDS piece dest (bytes)
  const int ldsp1 = ldsp0 + 1024;

#define STAGE_A(buf, mg, t) do { \
    gload_lds16(pA0 + (size_t)(mg) * 64 * K_IN + (t) * 64, &L[(buf) * 65536 + (mg) * 16384 + ldsp0]); \
    gload_lds16(pA1 + (size_t)(mg) * 64 * K_IN + (t) * 64, &L[(buf) * 65536 + (mg) * 16384 + ldsp1]); \
  } while (0)
#define STAGE_B(buf, ng, t) do { \
    gload_lds16(pB0 + (size_t)(ng) * 32 * K_IN + (t) * 64, &L[(buf) * 65536 + 32768 + (ng) * 16384 + ldsp0]); \
    gload_lds16(pB1 + (size_t)(ng) * 32 * K_IN + (t) * 64, &L[(buf) * 65536 + 32768 + (ng) * 16384 + ldsp1]); \
  } while (0)

  // ---- fragment-read precompute ----
  const int l15   = lane & 15;
  const int abase = wm * 8192 + l15 * 128;          // within A region [wh][64r][128B]
  const int bbase = 32768 + wn * 4096 + l15 * 128;  // within B region [128r][128B]
  const int sl0 = (((lane >> 4) + 0) ^ (lane & 7)) * 16; // swizzled 16B slot, ks=0
  const int sl1 = (((lane >> 4) + 4) ^ (lane & 7)) * 16; // ks=1

  short8 a[8], bl[4], br[4];

#define RD_A(buf, mg) do { \
    _Pragma("unroll") for (int mf = 0; mf < 4; ++mf) { \
      a[mf * 2 + 0] = *reinterpret_cast<const short8*>(&L[(buf) * 65536 + (mg) * 16384 + abase + mf * 2048 + sl0]); \
      a[mf * 2 + 1] = *reinterpret_cast<const short8*>(&L[(buf) * 65536 + (mg) * 16384 + abase + mf * 2048 + sl1]); \
    } } while (0)
#define RD_B(dst, buf, ng) do { \
    _Pragma("unroll") for (int nf = 0; nf < 2; ++nf) { \
      dst[nf * 2 + 0] = *reinterpret_cast<const short8*>(&L[(buf) * 65536 + (ng) * 16384 + bbase + nf * 2048 + sl0]); \
      dst[nf * 2 + 1] = *reinterpret_cast<const short8*>(&L[(buf) * 65536 + (ng) * 16384 + bbase + nf * 2048 + sl1]); \
    } } while (0)

  float4v acc[8][4];
#pragma unroll
  for (int i = 0; i < 8; ++i)
#pragma unroll
    for (int j = 0; j < 4; ++j) acc[i][j] = (float4v){0.f, 0.f, 0.f, 0.f};

#define DO_QUAD(mg, ng, bb_) do { \
    _Pragma("unroll") for (int ks = 0; ks < 2; ++ks) \
    _Pragma("unroll") for (int mf = 0; mf < 4; ++mf) \
    _Pragma("unroll") for (int nf = 0; nf < 2; ++nf) \
      acc[(mg) * 4 + mf][(ng) * 2 + nf] = \
        MFMA_BF16(a[mf * 2 + ks], bb_[nf * 2 + ks], acc[(mg) * 4 + mf][(ng) * 2 + nf], 0, 0, 0); \
  } while (0)

  // ---- prologue: kt0 (4 chunks, buf0) + kt1 tops+Bs (3 chunks, buf1) ----
  STAGE_A(0, 0, 0); STAGE_B(0, 1, 0); STAGE_B(0, 0, 0); STAGE_A(0, 1, 0);
  STAGE_A(1, 0, 1); STAGE_B(1, 1, 1); STAGE_B(1, 0, 1);
  VMCNT6();  // oldest 4 chunks (= all of kt0) landed
  BAR();

  // ---- main loop: i=0..30 computes kt=2i (buf0), kt+1 (buf1) ----
  // Single barrier per phase: {RD (at head, after publishing barrier); STAGE; MFMA; [vmcnt]; BAR}.
  for (int i = 0; i < NT / 2 - 1; ++i) {
    const int t2 = 2 * i + 2, t3 = 2 * i + 3;
    // ph1: Q1(kt) | stage kt+1.Abot -> buf1
    RD_A(0, 0); RD_B(br, 0, 1);
    STAGE_A(1, 1, t3 - 2);
    PRIO1(); DO_QUAD(0, 1, br); PRIO0(); BAR();
    // ph2: Q2(kt) | stage kt+2.Atop -> buf0 (last read ph1)
    RD_B(bl, 0, 0);
    STAGE_A(0, 0, t2);
    PRIO1(); DO_QUAD(0, 0, bl); PRIO0(); BAR();
    // ph3: Q3(kt) | stage kt+2.Bright -> buf0 (last read ph1)
    RD_A(0, 1);
    STAGE_B(0, 1, t2);
    PRIO1(); DO_QUAD(1, 0, bl); PRIO0(); BAR();
    // ph4: Q4(kt, br regs) | stage kt+2.Bleft -> buf0 (last read ph2) | vmcnt(6)
    STAGE_B(0, 0, t2);
    PRIO1(); DO_QUAD(1, 1, br); PRIO0();
    VMCNT6();  // kt+1 fully landed before ph5 reads buf1
    BAR();
    // ph5: Q1(kt+1) | stage kt+2.Abot -> buf0 (last read ph3)
    RD_A(1, 0); RD_B(br, 1, 1);
    STAGE_A(0, 1, t2);
    PRIO1(); DO_QUAD(0, 1, br); PRIO0(); BAR();
    // ph6: Q2(kt+1) | stage kt+3.Atop -> buf1 (last read ph5)
    RD_B(bl, 1, 0);
    STAGE_A(1, 0, t3);
    PRIO1(); DO_QUAD(0, 0, bl); PRIO0(); BAR();
    // ph7: Q3(kt+1) | stage kt+3.Bright -> buf1 (last read ph5)
    RD_A(1, 1);
    STAGE_B(1, 1, t3);
    PRIO1(); DO_QUAD(1, 0, bl); PRIO0(); BAR();
    // ph8: Q4(kt+1) | stage kt+3.Bleft -> buf1 (last read ph6) | vmcnt(6)
    STAGE_B(1, 0, t3);
    PRIO1(); DO_QUAD(1, 1, br); PRIO0();
    VMCNT6();  // kt+2 fully landed before next ph1 reads buf0
    BAR();
  }

  // ---- epilogue: kt=62 (buf0), kt=63 (buf1) ----
  RD_A(0, 0); RD_B(br, 0, 1);
  STAGE_A(1, 1, 63);  // kt63.Abot
  PRIO1(); DO_QUAD(0, 1, br); PRIO0(); BAR();
  RD_B(bl, 0, 0);
  PRIO1(); DO_QUAD(0, 0, bl); PRIO0(); BAR();
  RD_A(0, 1);
  PRIO1(); DO_QUAD(1, 0, bl); PRIO0();
  VMCNT0();  // kt63 fully landed before ph5' reads buf1
  BAR();
  PRIO1(); DO_QUAD(1, 1, br); PRIO0(); BAR();
  RD_A(1, 0); RD_B(br, 1, 1);
  PRIO1(); DO_QUAD(0, 1, br); PRIO0(); BAR();
  RD_B(bl, 1, 0);
  PRIO1(); DO_QUAD(0, 0, bl); PRIO0(); BAR();
  RD_A(1, 1);
  PRIO1(); DO_QUAD(1, 0, bl); PRIO0(); BAR();
  PRIO1(); DO_QUAD(1, 1, br); PRIO0();

  // ---- C write: col = o0 + wn*64 + nf*16 + (lane&15); row = m0 + wm*128 + mf*16 + (lane>>4)*4 + r
#pragma unroll
  for (int nf = 0; nf < 4; ++nf) {
    const int col = o0 + wn * 64 + nf * 16 + l15;
    const float bb = bias[col];
#pragma unroll
    for (int mf = 0; mf < 8; ++mf) {
      const int rowb = m0 + wm * 128 + mf * 16 + (lane >> 4) * 4;
#pragma unroll
      for (int r = 0; r < 4; ++r)
        out[(size_t)(rowb + r) * N_OUT + col] = acc[mf][nf][r] + bb;
    }
  }
}

extern "C" void kernel_launch(void* const* d_in, const int* in_sizes, int n_in,
                              void* d_out, int out_size, void* d_ws, size_t ws_size,
                              hipStream_t stream) {
  const float* x    = (const float*)d_in[0];
  const int* wp     = (const int*)d_in[1];
  const float* wsc  = (const float*)d_in[2];
  const float* wzr  = (const float*)d_in[3];
  const float* bias = (const float*)d_in[4];
  float* out = (float*)d_out;

  const size_t xb_bytes = (size_t)M_TOTAL * K_IN * 2;
  short* xb = (short*)d_ws;
  short* wb = (short*)((char*)d_ws + xb_bytes);

  prep_kernel<<<4096, 256, 0, stream>>>(x, xb, wp, wsc, wzr, wb);
  qgemm8_kernel<<<dim3(512), dim3(512), 0, stream>>>(xb, wb, bias, out);
}